// Round 1
// baseline (1655.307 us; speedup 1.0000x reference)
//
#include <hip/hip_runtime.h>
#include <hip/hip_bf16.h>
#include <cstdint>

// ---------------------------------------------------------------------------
// Problem constants
// ---------------------------------------------------------------------------
#define B_   4
#define T_   8192
#define D_   128
#define M_   8
#define BT_  (B_*T_)          // 32768 tokens
#define NC_  64               // scan chunks
#define LCH_ (T_/NC_)         // 128 steps/chunk
#define Z_OFF (BT_*D_)        // d_out: [y (BT*D)] [z (BT*D)]

// workspace layout (bytes)
#define WS_PI    256
#define WS_W12   (WS_PI  + BT_*M_*4)        // 128x1024 bf16
#define WS_W2    (WS_W12 + 128*1024*2)      // 128x2048 bf16
#define WS_S     (WS_W2  + 128*2048*2)      // chunk end-states
#define WS_ZST   (WS_S   + NC_*B_*64*2*4)   // chunk start-states
// total ~2.1 MB

typedef float f32x4 __attribute__((ext_vector_type(4)));
typedef short short8 __attribute__((ext_vector_type(8)));

__device__ __forceinline__ unsigned short f2bf(float f){
  union { float f; uint32_t u; } v; v.f = f;
  return (unsigned short)((v.u + 0x7FFFu + ((v.u >> 16) & 1u)) >> 16);
}
__device__ __forceinline__ float sigmoidf_(float x){ return 1.0f/(1.0f + __expf(-x)); }
__device__ __forceinline__ float scale_from(const float* s8){
  float s = 1.0f;
  #pragma unroll
  for (int m=0;m<M_;m++) s = fmaxf(s, s8[m]);
  return s;
}

// ---------------------------------------------------------------------------
// K1: gate softmax pi + weight packing (bf16)
// blocks [0, BT_/4): one wave per token.  blocks [BT_/4, +384): packing.
// ---------------------------------------------------------------------------
__global__ void prep_kernel(const float* __restrict__ u,
                            const float* __restrict__ gate_w,
                            const float* __restrict__ gate_b,
                            const float* __restrict__ K12,
                            const float* __restrict__ K21,
                            const float* __restrict__ K22,
                            float* __restrict__ pi_out,
                            unsigned short* __restrict__ w12,
                            unsigned short* __restrict__ w2)
{
  int bid = blockIdx.x;
  if (bid < BT_/4) {
    int wid = threadIdx.x >> 6, lane = threadIdx.x & 63;
    int bt = bid*4 + wid;
    float2 u2 = *(const float2*)(u + bt*D_ + lane*2);
    float lg[M_];
    #pragma unroll
    for (int m=0;m<M_;m++){
      float2 g2 = *(const float2*)(gate_w + m*D_ + lane*2);
      lg[m] = u2.x*g2.x + u2.y*g2.y;
    }
    #pragma unroll
    for (int off=32; off>=1; off>>=1){
      #pragma unroll
      for (int m=0;m<M_;m++) lg[m] += __shfl_xor(lg[m], off);
    }
    #pragma unroll
    for (int m=0;m<M_;m++) lg[m] += gate_b[m];
    float mx = lg[0];
    #pragma unroll
    for (int m=1;m<M_;m++) mx = fmaxf(mx, lg[m]);
    float e[M_]; float s = 0.f;
    #pragma unroll
    for (int m=0;m<M_;m++){ e[m] = __expf(lg[m]-mx); s += e[m]; }
    float inv = 1.0f/s;
    if (lane == 0){
      float* po = pi_out + bt*M_;
      *(float4*)(po)   = make_float4(e[0]*inv,e[1]*inv,e[2]*inv,e[3]*inv);
      *(float4*)(po+4) = make_float4(e[4]*inv,e[5]*inv,e[6]*inv,e[7]*inv);
    }
  } else {
    int idx = (bid - BT_/4)*1024 + threadIdx.x*4;
    #pragma unroll
    for (int t=0;t<4;t++){
      int i = idx + t;
      if (i < 128*1024){                   // W12[s, m*128+u] = K12[m,s,u]
        int s_ = i >> 10, kk = i & 1023;
        int mm = kk >> 7, uu = kk & 127;
        w12[i] = f2bf(K12[(mm*D_ + s_)*D_ + uu]);
      } else {                             // W2[y, kk]: kk<1024 -> K22, else K21
        int j = i - 128*1024;
        int y_ = j >> 11, kk = j & 2047;
        float val;
        if (kk < 1024){ int mm = kk>>7, uu = kk&127; val = K22[(mm*D_ + y_)*D_ + uu]; }
        else { int kk2 = kk-1024; int mm = kk2>>7, ss = kk2&127; val = K21[(mm*D_ + y_)*D_ + ss]; }
        w2[j] = f2bf(val);
      }
    }
  }
}

// ---------------------------------------------------------------------------
// K2: sigma_max of each expert's 256x256 K_raw via shifted power iteration
// on B = K^T K.  One block/expert, 1024 threads.  Each thread owns a 4x16
// tile of K (rows) and of K^T (via one-time LDS transpose) in registers.
// x kept in padded LDS (float4 units padded every 8 units -> <=2-way bank).
// ---------------------------------------------------------------------------
#define SIG_IT 192
#define SIG_SHIFT_IT 48
#define STW 260
__device__ __forceinline__ int padu_(int unit){ return unit*4 + (unit>>3)*4; }

__global__ __launch_bounds__(1024) void sigma_kernel(
    const float* __restrict__ rho_raw, const float* __restrict__ theta,
    const float* __restrict__ K12, const float* __restrict__ K21,
    const float* __restrict__ K22, float* __restrict__ sig_out)
{
  __shared__ float stage[64*STW];
  __shared__ float xvp[304], yvp[304], xnp[304];
  __shared__ float red[2];
  const int m   = blockIdx.x;
  const int tid = threadIdx.x;
  const int rg  = tid >> 4;      // 0..63 : row-group (4 rows)
  const int cg  = tid & 15;      // 0..15 : col-group (16 cols)
  const int r0  = rg*4;
  const int c0  = cg*16;

  // ---- row tile rowk[i][j] = K[r0+i][c0+j]
  float rowk[4][16];
  {
    const bool rlow = (r0 < 128), clow = (c0 < 128);
    if (rlow && clow) {            // K11 block-diagonal 2x2 rotations
      int p0 = r0 >> 1;
      float rho0 = sigmoidf_(rho_raw[p0])   * 0.999f;
      float rho1 = sigmoidf_(rho_raw[p0+1]) * 0.999f;
      float c_0 = cosf(theta[p0]),   s_0 = sinf(theta[p0]);
      float c_1 = cosf(theta[p0+1]), s_1 = sinf(theta[p0+1]);
      #pragma unroll
      for (int i=0;i<4;i++){
        int   p  = (i<2)? p0 : p0+1;
        float rc = (i<2)? rho0*c_0 : rho1*c_1;
        float rs = (i<2)? rho0*s_0 : rho1*s_1;
        float e0 = ((i&1)==0)?  rc : rs;
        float e1 = ((i&1)==0)? -rs : rc;
        int cc = 2*p;
        #pragma unroll
        for (int j=0;j<16;j++){
          int c = c0 + j;
          rowk[i][j] = (c == cc) ? e0 : ((c == cc+1) ? e1 : 0.0f);
        }
      }
    } else {
      const float* base;
      if (rlow)      base = K12 + (m*128 + r0)*128       + (c0 - 128);
      else if (clow) base = K21 + (m*128 + (r0-128))*128 + c0;
      else           base = K22 + (m*128 + (r0-128))*128 + (c0 - 128);
      #pragma unroll
      for (int i=0;i<4;i++){
        #pragma unroll
        for (int j4=0;j4<4;j4++){
          float4 v = *(const float4*)(base + i*128 + j4*4);
          rowk[i][j4*4+0]=v.x; rowk[i][j4*4+1]=v.y; rowk[i][j4*4+2]=v.z; rowk[i][j4*4+3]=v.w;
        }
      }
    }
  }
  // ---- one-time LDS transpose: colk[i][j] = K[c0+j][r0+i]
  float colk[4][16];
  #pragma unroll
  for (int g=0; g<4; ++g){
    if ((rg >> 4) == g){
      #pragma unroll
      for (int i=0;i<4;i++){
        int rr = r0 + i - g*64;
        #pragma unroll
        for (int j4=0;j4<4;j4++)
          *(float4*)&stage[rr*STW + c0 + j4*4] =
            make_float4(rowk[i][j4*4],rowk[i][j4*4+1],rowk[i][j4*4+2],rowk[i][j4*4+3]);
      }
    }
    __syncthreads();
    if ((cg >> 2) == g){
      #pragma unroll
      for (int j=0;j<16;j++){
        int sr = c0 + j - g*64;
        float4 v = *(const float4*)&stage[sr*STW + r0];
        colk[0][j]=v.x; colk[1][j]=v.y; colk[2][j]=v.z; colk[3][j]=v.w;
      }
    }
    __syncthreads();
  }
  // ---- init x
  if (tid < 256){
    int un = tid>>2, j = tid&3;
    xvp[padu_(un)+j] = 1.0f + 0.25f*__sinf(0.731f*(float)tid);
  }
  __syncthreads();

  float cshift = 0.0f, lam = 0.0f;
  for (int it=0; it<SIG_IT; ++it){
    // phase 1: y = K x
    float xs[16];
    #pragma unroll
    for (int i4=0;i4<4;i4++){
      float4 v = *(const float4*)&xvp[padu_(4*cg+i4)];
      xs[i4*4+0]=v.x; xs[i4*4+1]=v.y; xs[i4*4+2]=v.z; xs[i4*4+3]=v.w;
    }
    float py[4];
    #pragma unroll
    for (int i=0;i<4;i++){
      float a = 0.f;
      #pragma unroll
      for (int j=0;j<16;j++) a = fmaf(rowk[i][j], xs[j], a);
      py[i] = a;
    }
    #pragma unroll
    for (int off=8; off>=1; off>>=1){
      #pragma unroll
      for (int i=0;i<4;i++) py[i] += __shfl_xor(py[i], off);
    }
    if (cg == 0)
      *(float4*)&yvp[padu_(rg)] = make_float4(py[0],py[1],py[2],py[3]);
    __syncthreads();
    // phase 2: xn = K^T y - cshift*x
    float ys[16];
    #pragma unroll
    for (int i4=0;i4<4;i4++){
      float4 v = *(const float4*)&yvp[padu_(4*cg+i4)];
      ys[i4*4+0]=v.x; ys[i4*4+1]=v.y; ys[i4*4+2]=v.z; ys[i4*4+3]=v.w;
    }
    float px[4];
    #pragma unroll
    for (int i=0;i<4;i++){
      float a = 0.f;
      #pragma unroll
      for (int j=0;j<16;j++) a = fmaf(colk[i][j], ys[j], a);
      px[i] = a;
    }
    #pragma unroll
    for (int off=8; off>=1; off>>=1){
      #pragma unroll
      for (int i=0;i<4;i++) px[i] += __shfl_xor(px[i], off);
    }
    if (cg == 0){
      float4 xo = *(const float4*)&xvp[padu_(rg)];
      *(float4*)&xnp[padu_(rg)] = make_float4(px[0]-cshift*xo.x, px[1]-cshift*xo.y,
                                              px[2]-cshift*xo.z, px[3]-cshift*xo.w);
    }
    __syncthreads();
    // norm + Rayleigh
    if (tid < 64){
      float4 a = *(const float4*)&xnp[padu_(tid)];
      float4 b = *(const float4*)&xvp[padu_(tid)];
      float n2 = a.x*a.x+a.y*a.y+a.z*a.z+a.w*a.w;
      float dp = a.x*b.x+a.y*b.y+a.z*b.z+a.w*b.w;
      #pragma unroll
      for (int off=32; off>=1; off>>=1){ n2 += __shfl_xor(n2,off); dp += __shfl_xor(dp,off); }
      if (tid == 0){ red[0]=n2; red[1]=dp; }
    }
    __syncthreads();
    float n2 = red[0];
    lam = red[1] + cshift;            // x^T B x  (||x||=1 after first iter)
    float inv = rsqrtf(n2);
    if (tid < 256){
      int un = tid>>2, j = tid&3;
      xvp[padu_(un)+j] = xnp[padu_(un)+j]*inv;
    }
    if (it == SIG_SHIFT_IT-1) cshift = 0.45f*lam;
    __syncthreads();
  }
  if (tid == 0) sig_out[m] = sqrtf(fmaxf(lam, 0.0f));
}

// ---------------------------------------------------------------------------
// GEMM: out[32768x128] = A[32768xKTOT] * Wpack^T, A built on the fly:
//   kk < 1024 : A[bt,kk] = pi[bt, kk>>7] * u[bt, kk&127]
//   kk >= 1024: A[bt,kk] = pi[bt,(kk-1024)>>7] * z[bt,(kk-1024)&127]
// epilogue scales by 1/scale.  128x128 tile, 4 waves, mfma 16x16x32 bf16.
// ---------------------------------------------------------------------------
template<int KTOT, bool SECOND>
__global__ __launch_bounds__(256) void gemm_kernel(
    const float* __restrict__ u, const float* __restrict__ zsrc,
    const float* __restrict__ pi, const unsigned short* __restrict__ wpack,
    float* __restrict__ out, const float* __restrict__ sig8)
{
  float inv_s = 1.0f / scale_from(sig8);
  __shared__ unsigned short a_lds[128*64];
  __shared__ unsigned short b_lds[128*64];
  const int tid  = threadIdx.x;
  const int lane = tid & 63;
  const int wid  = tid >> 6;
  const int wr   = wid >> 1, wc = wid & 1;
  const int bt0  = blockIdx.x * 128;
  f32x4 acc[4][4];
  #pragma unroll
  for (int a=0;a<4;a++){
    #pragma unroll
    for (int b=0;b<4;b++) acc[a][b] = (f32x4){0.f,0.f,0.f,0.f};
  }
  const int r = tid >> 1, half = tid & 1;
  for (int kk0 = 0; kk0 < KTOT; kk0 += 64){
    { // A-stage (reg-staged: fp32 load, *pi, ->bf16)
      const float* src; int mm, j0;
      if (!SECOND || kk0 < 1024){ mm = kk0 >> 7; j0 = (kk0 & 127) + half*32; src = u + (bt0+r)*D_ + j0; }
      else { int k2 = kk0 - 1024; mm = k2 >> 7; j0 = (k2 & 127) + half*32; src = zsrc + (bt0+r)*D_ + j0; }
      float pv = pi[(bt0+r)*M_ + mm];
      unsigned short* dst = &a_lds[r*64 + half*32];
      #pragma unroll
      for (int i=0;i<8;i++){
        float4 v = *(const float4*)(src + i*4);
        ushort4 w;
        w.x=f2bf(v.x*pv); w.y=f2bf(v.y*pv); w.z=f2bf(v.z*pv); w.w=f2bf(v.w*pv);
        *(ushort4*)(dst + i*4) = w;
      }
      // B-stage (bf16 pack, N x K row-major = B^T layout)
      const unsigned short* srcb = wpack + r*KTOT + kk0 + half*32;
      uint4* dstb = (uint4*)&b_lds[r*64 + half*32];
      #pragma unroll
      for (int i=0;i<4;i++) dstb[i] = *(const uint4*)(srcb + i*8);
    }
    __syncthreads();
    #pragma unroll
    for (int ks=0; ks<2; ks++){
      short8 af[4], bfr[4];
      #pragma unroll
      for (int f=0; f<4; f++){
        int ar_ = wr*64 + f*16 + (lane&15);
        af[f]  = *(const short8*)&a_lds[ar_*64 + ks*32 + (lane>>4)*8];
        int bn  = wc*64 + f*16 + (lane&15);
        bfr[f] = *(const short8*)&b_lds[bn*64 + ks*32 + (lane>>4)*8];
      }
      #pragma unroll
      for (int fr=0; fr<4; fr++){
        #pragma unroll
        for (int fc=0; fc<4; fc++)
          acc[fr][fc] = __builtin_amdgcn_mfma_f32_16x16x32_bf16(af[fr], bfr[fc], acc[fr][fc], 0,0,0);
      }
    }
    __syncthreads();
  }
  #pragma unroll
  for (int fr=0; fr<4; fr++){
    #pragma unroll
    for (int fc=0; fc<4; fc++){
      #pragma unroll
      for (int rr=0; rr<4; rr++){
        int row = bt0 + wr*64 + fr*16 + (lane>>4)*4 + rr;
        int col = wc*64 + fc*16 + (lane&15);
        out[row*D_ + col] = acc[fr][fc][rr]*inv_s;
      }
    }
  }
}

// ---------------------------------------------------------------------------
// Scan: z block-diag 2x2 rotations => 256 independent complex recurrences.
// 3-phase exact chunked scan. v lives in the y-region of d_out (already /scale).
// Reference emits carry BEFORE consuming v[t]  (z[0] = 0).
// ---------------------------------------------------------------------------
__global__ void scan_a(const float* __restrict__ v, const float* __restrict__ rho_raw,
                       const float* __restrict__ theta, const float* __restrict__ sig8,
                       float* __restrict__ Ssum)
{
  int b = blockIdx.x >> 6, c = blockIdx.x & 63;
  int p = threadIdx.x;
  float sc  = scale_from(sig8);
  float rho = sigmoidf_(rho_raw[p]) * 0.999f / sc;
  float th  = theta[p];
  float ar = rho*cosf(th), ai = rho*sinf(th);
  const float2* vp = (const float2*)v + (b*T_ + c*LCH_)*64 + p;
  float zx=0.f, zy=0.f;
  #pragma unroll 4
  for (int t=0; t<LCH_; ++t){
    float2 vt = vp[t*64];
    float nx = fmaf(ar, zx, fmaf(-ai, zy, vt.x));
    float ny = fmaf(ai, zx, fmaf( ar, zy, vt.y));
    zx = nx; zy = ny;
  }
  ((float2*)Ssum)[(b*NC_ + c)*64 + p] = make_float2(zx, zy);
}

__global__ void scan_b(const float* __restrict__ Ssum, float* __restrict__ Zst,
                       const float* __restrict__ rho_raw, const float* __restrict__ theta,
                       const float* __restrict__ sig8)
{
  int tid = threadIdx.x;          // 256 = B_*64
  int b = tid >> 6, p = tid & 63;
  float sc  = scale_from(sig8);
  float rho = sigmoidf_(rho_raw[p]) * 0.999f / sc;
  float th  = theta[p];
  float qr = rho*cosf(th), qi = rho*sinf(th);
  #pragma unroll
  for (int s=0;s<7;s++){ float nr = qr*qr - qi*qi; float ni = 2.f*qr*qi; qr=nr; qi=ni; } // a^128
  float Zx=0.f, Zy=0.f;
  const float2* S = (const float2*)Ssum;
  float2* Z = (float2*)Zst;
  for (int c=0;c<NC_;c++){
    Z[(b*NC_+c)*64 + p] = make_float2(Zx, Zy);
    float2 s = S[(b*NC_+c)*64 + p];
    float nx = qr*Zx - qi*Zy + s.x;
    float ny = qi*Zx + qr*Zy + s.y;
    Zx = nx; Zy = ny;
  }
}

__global__ void scan_c(const float* __restrict__ v, const float* __restrict__ Zst,
                       const float* __restrict__ rho_raw, const float* __restrict__ theta,
                       const float* __restrict__ sig8, float* __restrict__ zout)
{
  int b = blockIdx.x >> 6, c = blockIdx.x & 63;
  int p = threadIdx.x;
  float sc  = scale_from(sig8);
  float rho = sigmoidf_(rho_raw[p]) * 0.999f / sc;
  float th  = theta[p];
  float ar = rho*cosf(th), ai = rho*sinf(th);
  const float2* vp = (const float2*)v + (b*T_ + c*LCH_)*64 + p;
  float2*       zp = (float2*)zout    + (b*T_ + c*LCH_)*64 + p;
  float2 z0 = ((const float2*)Zst)[(b*NC_+c)*64 + p];
  float zx = z0.x, zy = z0.y;
  #pragma unroll 4
  for (int t=0; t<LCH_; ++t){
    zp[t*64] = make_float2(zx, zy);      // emit BEFORE consuming v[t]
    float2 vt = vp[t*64];
    float nx = fmaf(ar, zx, fmaf(-ai, zy, vt.x));
    float ny = fmaf(ai, zx, fmaf( ar, zy, vt.y));
    zx = nx; zy = ny;
  }
}

// ---------------------------------------------------------------------------
extern "C" void kernel_launch(void* const* d_in, const int* in_sizes, int n_in,
                              void* d_out, int out_size, void* d_ws, size_t ws_size,
                              hipStream_t stream)
{
  const float* u       = (const float*)d_in[0];
  const float* rho_raw = (const float*)d_in[1];
  const float* theta   = (const float*)d_in[2];
  const float* K12     = (const float*)d_in[3];
  const float* K21     = (const float*)d_in[4];
  const float* K22     = (const float*)d_in[5];
  const float* gate_w  = (const float*)d_in[6];
  const float* gate_b  = (const float*)d_in[7];
  float* out = (float*)d_out;
  char*  ws  = (char*)d_ws;
  float* sig8 = (float*)ws;
  float* pi   = (float*)(ws + WS_PI);
  unsigned short* w12 = (unsigned short*)(ws + WS_W12);
  unsigned short* w2  = (unsigned short*)(ws + WS_W2);
  float* Ssum = (float*)(ws + WS_S);
  float* Zst  = (float*)(ws + WS_ZST);
  float* v    = out;            // y-region doubles as v scratch until GEMM2
  float* zout = out + Z_OFF;

  hipLaunchKernelGGL(prep_kernel, dim3(BT_/4 + 384), dim3(256), 0, stream,
                     u, gate_w, gate_b, K12, K21, K22, pi, w12, w2);
  hipLaunchKernelGGL(sigma_kernel, dim3(8), dim3(1024), 0, stream,
                     rho_raw, theta, K12, K21, K22, sig8);
  hipLaunchKernelGGL((gemm_kernel<1024,false>), dim3(256), dim3(256), 0, stream,
                     u, u, pi, w12, v, sig8);
  hipLaunchKernelGGL(scan_a, dim3(B_*NC_), dim3(64), 0, stream, v, rho_raw, theta, sig8, Ssum);
  hipLaunchKernelGGL(scan_b, dim3(1), dim3(256), 0, stream, Ssum, Zst, rho_raw, theta, sig8);
  hipLaunchKernelGGL(scan_c, dim3(B_*NC_), dim3(64), 0, stream, v, Zst, rho_raw, theta, sig8, zout);
  hipLaunchKernelGGL((gemm_kernel<2048,true>), dim3(256), dim3(256), 0, stream,
                     u, zout, pi, w2, out, sig8);
}

// Round 2
// 850.944 us; speedup vs baseline: 1.9453x; 1.9453x over previous
//
#include <hip/hip_runtime.h>
#include <hip/hip_bf16.h>
#include <cstdint>

// ---------------------------------------------------------------------------
// Problem constants
// ---------------------------------------------------------------------------
#define B_   4
#define T_   8192
#define D_   128
#define M_   8
#define BT_  (B_*T_)          // 32768 tokens
#define NC_  256              // scan chunks (32 steps each)
#define LCH_ (T_/NC_)         // 32 steps/chunk
#define Z_OFF (BT_*D_)        // d_out: [y (BT*D)] [z (BT*D)]

// workspace layout (bytes)
#define WS_PI    256
#define WS_W12   (WS_PI  + BT_*M_*4)        // 128x1024 bf16
#define WS_W2    (WS_W12 + 128*1024*2)      // 128x2048 bf16
#define WS_S     (WS_W2  + 128*2048*2)      // chunk end-states
#define WS_ZST   (WS_S   + NC_*B_*64*2*4)   // chunk start-states
// total ~2.8 MB

typedef float f32x4 __attribute__((ext_vector_type(4)));
typedef short short8 __attribute__((ext_vector_type(8)));

__device__ __forceinline__ unsigned short f2bf(float f){
  union { float f; uint32_t u; } v; v.f = f;
  return (unsigned short)((v.u + 0x7FFFu + ((v.u >> 16) & 1u)) >> 16);
}
__device__ __forceinline__ float sigmoidf_(float x){ return 1.0f/(1.0f + __expf(-x)); }
__device__ __forceinline__ float scale_from(const float* s8){
  float s = 1.0f;
  #pragma unroll
  for (int m=0;m<M_;m++) s = fmaxf(s, s8[m]);
  return s;
}
// butterfly add over lane bits 0,1 via DPP quad_perm (VALU-only, no DS)
__device__ __forceinline__ float dpp_red4(float x){
  x += __int_as_float(__builtin_amdgcn_mov_dpp(__float_as_int(x), 0xB1, 0xF, 0xF, 1)); // xor 1
  x += __int_as_float(__builtin_amdgcn_mov_dpp(__float_as_int(x), 0x4E, 0xF, 0xF, 1)); // xor 2
  return x;
}

// ---------------------------------------------------------------------------
// K1: gate softmax pi + weight packing (bf16)
// ---------------------------------------------------------------------------
__global__ void prep_kernel(const float* __restrict__ u,
                            const float* __restrict__ gate_w,
                            const float* __restrict__ gate_b,
                            const float* __restrict__ K12,
                            const float* __restrict__ K21,
                            const float* __restrict__ K22,
                            float* __restrict__ pi_out,
                            unsigned short* __restrict__ w12,
                            unsigned short* __restrict__ w2)
{
  int bid = blockIdx.x;
  if (bid < BT_/4) {
    int wid = threadIdx.x >> 6, lane = threadIdx.x & 63;
    int bt = bid*4 + wid;
    float2 u2 = *(const float2*)(u + bt*D_ + lane*2);
    float lg[M_];
    #pragma unroll
    for (int m=0;m<M_;m++){
      float2 g2 = *(const float2*)(gate_w + m*D_ + lane*2);
      lg[m] = u2.x*g2.x + u2.y*g2.y;
    }
    #pragma unroll
    for (int off=32; off>=1; off>>=1){
      #pragma unroll
      for (int m=0;m<M_;m++) lg[m] += __shfl_xor(lg[m], off);
    }
    #pragma unroll
    for (int m=0;m<M_;m++) lg[m] += gate_b[m];
    float mx = lg[0];
    #pragma unroll
    for (int m=1;m<M_;m++) mx = fmaxf(mx, lg[m]);
    float e[M_]; float s = 0.f;
    #pragma unroll
    for (int m=0;m<M_;m++){ e[m] = __expf(lg[m]-mx); s += e[m]; }
    float inv = 1.0f/s;
    if (lane == 0){
      float* po = pi_out + bt*M_;
      *(float4*)(po)   = make_float4(e[0]*inv,e[1]*inv,e[2]*inv,e[3]*inv);
      *(float4*)(po+4) = make_float4(e[4]*inv,e[5]*inv,e[6]*inv,e[7]*inv);
    }
  } else {
    int idx = (bid - BT_/4)*1024 + threadIdx.x*4;
    #pragma unroll
    for (int t=0;t<4;t++){
      int i = idx + t;
      if (i < 128*1024){                   // W12[s, m*128+u] = K12[m,s,u]
        int s_ = i >> 10, kk = i & 1023;
        int mm = kk >> 7, uu = kk & 127;
        w12[i] = f2bf(K12[(mm*D_ + s_)*D_ + uu]);
      } else {                             // W2[y, kk]: kk<1024 -> K22, else K21
        int j = i - 128*1024;
        int y_ = j >> 11, kk = j & 2047;
        float val;
        if (kk < 1024){ int mm = kk>>7, uu = kk&127; val = K22[(mm*D_ + y_)*D_ + uu]; }
        else { int kk2 = kk-1024; int mm = kk2>>7, ss = kk2&127; val = K21[(mm*D_ + y_)*D_ + ss]; }
        w2[j] = f2bf(val);
      }
    }
  }
}

// ---------------------------------------------------------------------------
// K2: sigma_max per expert via shifted power iteration on B = K^T K.
// 256 threads (4 waves = 1/SIMD -> 512 VGPR cap).  Thread (rg=tid>>2, cg=tid&3)
// owns rows r0..r0+3 x cols c0..c0+63:  rowk fp32 (256 regs), colk = K^T tile
// bf16-packed (128 regs).  Deferred normalization (every 16 iters), 2
// barriers/iter, DPP reduces over the 2 cg lane-bits.  Final sigma = ||K x||.
// ---------------------------------------------------------------------------
#define SIG_IT 128
// x/y vectors: 64 float4 units, padded 16B every 8 units -> conflict-free b128
__device__ __forceinline__ int padf_(int unit){ return unit*4 + (unit>>3)*4; }

__global__ __launch_bounds__(256, 1) void sigma_kernel(
    const float* __restrict__ rho_raw, const float* __restrict__ theta,
    const float* __restrict__ K12, const float* __restrict__ K21,
    const float* __restrict__ K22, float* __restrict__ sig_out)
{
  __shared__ float xv[304], yv[304];
  __shared__ float red[2];
  const int m   = blockIdx.x;
  const int tid = threadIdx.x;
  const int rg  = tid >> 2;      // 0..63
  const int cg  = tid & 3;       // 0..3
  const int r0  = rg*4;
  const int c0  = cg*64;
  const bool rlow = (r0 < 128), clow = (c0 < 128);

  // pair params for this thread's rows (only used when r0<128)
  float rc0=0.f, rs0=0.f, rc1=0.f, rs1=0.f;
  if (rlow){
    int p0 = r0 >> 1;            // = 2*rg
    float rho0 = sigmoidf_(rho_raw[p0])   * 0.999f;
    float rho1 = sigmoidf_(rho_raw[p0+1]) * 0.999f;
    rc0 = rho0*cosf(theta[p0]);   rs0 = rho0*sinf(theta[p0]);
    rc1 = rho1*cosf(theta[p0+1]); rs1 = rho1*sinf(theta[p0+1]);
  }

  // ---- rowk[i][j] = K[r0+i][c0+j]  (fp32, 256 VGPRs)
  float rowk[4][64];
  if (rlow && clow) {
    #pragma unroll
    for (int i=0;i<4;i++){
      int a = r0 + i; int p = a >> 1;
      float rcv = (i<2)? rc0 : rc1;
      float rsv = (i<2)? rs0 : rs1;
      float v0 = (a&1)? rsv : rcv;          // col 2p
      float v1 = (a&1)? rcv : -rsv;         // col 2p+1
      #pragma unroll
      for (int j=0;j<64;j++){
        int c = c0 + j;
        rowk[i][j] = (c == 2*p) ? v0 : ((c == 2*p+1) ? v1 : 0.0f);
      }
    }
  } else {
    const float* base;
    if (rlow)      base = K12 + (m*128 + r0)*128       + (c0 - 128);
    else if (clow) base = K21 + (m*128 + (r0-128))*128 + c0;
    else           base = K22 + (m*128 + (r0-128))*128 + (c0 - 128);
    #pragma unroll
    for (int i=0;i<4;i++){
      #pragma unroll
      for (int j4=0;j4<16;j4++){
        float4 v = *(const float4*)(base + i*128 + j4*4);
        rowk[i][4*j4+0]=v.x; rowk[i][4*j4+1]=v.y; rowk[i][4*j4+2]=v.z; rowk[i][4*j4+3]=v.w;
      }
    }
  }

  // ---- colk[i][kk] = pack_bf16( K[c0+2kk][r0+i], K[c0+2kk+1][r0+i] )
  uint32_t colk[4][32];
  {
    const float* base2 = nullptr; int roff = 0;
    if (clow && !rlow)      { base2 = K12 + m*128*128; roff = r0 - 128; } // rows a<128, col right
    else if (!clow && rlow) { base2 = K21 + m*128*128; roff = r0;       } // rows a>=128, col left
    else if (!clow && !rlow){ base2 = K22 + m*128*128; roff = r0 - 128; }
    #pragma unroll
    for (int kk=0; kk<32; ++kk){
      int a0 = c0 + 2*kk, a1 = a0 + 1;
      float va[4], vb[4];
      if (rlow && clow){                    // K11[a][b], b=r0+i
        #pragma unroll
        for (int i=0;i<4;i++){
          int b = r0 + i;
          float rcv = (i<2)? rc0 : rc1;
          float rsv = (i<2)? rs0 : rs1;
          float v0 = ((a0>>1)==(b>>1)) ? ( (((a0^b)&1)==0) ? rcv : ((a0&1)? rsv : -rsv) ) : 0.f;
          float v1 = ((a1>>1)==(b>>1)) ? ( (((a1^b)&1)==0) ? rcv : ((a1&1)? rsv : -rsv) ) : 0.f;
          va[i]=v0; vb[i]=v1;
        }
      } else {
        int aa0 = clow ? a0 : a0-128, aa1 = clow ? a1 : a1-128;
        float4 f0 = *(const float4*)(base2 + aa0*128 + roff);
        float4 f1 = *(const float4*)(base2 + aa1*128 + roff);
        va[0]=f0.x; va[1]=f0.y; va[2]=f0.z; va[3]=f0.w;
        vb[0]=f1.x; vb[1]=f1.y; vb[2]=f1.z; vb[3]=f1.w;
      }
      #pragma unroll
      for (int i=0;i<4;i++)
        colk[i][kk] = (uint32_t)f2bf(va[i]) | ((uint32_t)f2bf(vb[i]) << 16);
    }
  }

  // ---- init x (unnormalized)
  xv[padf_(tid>>2) + (tid&3)] = 1.0f + 0.25f*__sinf(0.731f*(float)tid);
  __syncthreads();

  float cshift = 0.0f;
  for (int it=0; it<SIG_IT; ++it){
    // phase 1: y = K x
    float py[4] = {0.f,0.f,0.f,0.f};
    #pragma unroll
    for (int j4=0;j4<16;j4++){
      float4 x4 = *(const float4*)&xv[padf_(cg*16 + j4)];
      #pragma unroll
      for (int i=0;i<4;i++){
        py[i] = fmaf(rowk[i][4*j4+0], x4.x, py[i]);
        py[i] = fmaf(rowk[i][4*j4+1], x4.y, py[i]);
        py[i] = fmaf(rowk[i][4*j4+2], x4.z, py[i]);
        py[i] = fmaf(rowk[i][4*j4+3], x4.w, py[i]);
      }
    }
    #pragma unroll
    for (int i=0;i<4;i++) py[i] = dpp_red4(py[i]);
    if (cg == 0)
      *(float4*)&yv[padf_(rg)] = make_float4(py[0],py[1],py[2],py[3]);
    __syncthreads();
    // phase 2: x' = K^T y - cshift*x   (colk bf16)
    float px[4] = {0.f,0.f,0.f,0.f};
    #pragma unroll
    for (int kk=0;kk<16;kk++){
      float4 y4 = *(const float4*)&yv[padf_(cg*16 + kk)];
      #pragma unroll
      for (int i=0;i<4;i++){
        uint32_t p0 = colk[i][2*kk], p1 = colk[i][2*kk+1];
        px[i] = fmaf(__int_as_float((int)(p0 << 16)),        y4.x, px[i]);
        px[i] = fmaf(__int_as_float((int)(p0 & 0xffff0000u)), y4.y, px[i]);
        px[i] = fmaf(__int_as_float((int)(p1 << 16)),        y4.z, px[i]);
        px[i] = fmaf(__int_as_float((int)(p1 & 0xffff0000u)), y4.w, px[i]);
      }
    }
    #pragma unroll
    for (int i=0;i<4;i++) px[i] = dpp_red4(px[i]);
    if (cg == 0){
      float4 xo = *(const float4*)&xv[padf_(rg)];
      *(float4*)&xv[padf_(rg)] = make_float4(px[0]-cshift*xo.x, px[1]-cshift*xo.y,
                                             px[2]-cshift*xo.z, px[3]-cshift*xo.w);
    }
    __syncthreads();
    // renormalize every 16 iters; set shift from norm growth at it==31
    if ((it & 15) == 15){
      float4 xx;
      if (tid < 64){
        xx = *(const float4*)&xv[padf_(tid)];
        float n2 = xx.x*xx.x + xx.y*xx.y + xx.z*xx.z + xx.w*xx.w;
        #pragma unroll
        for (int off=32; off>=1; off>>=1) n2 += __shfl_xor(n2, off);
        if (tid == 0) red[0] = n2;
      }
      __syncthreads();
      float n2 = red[0];
      if (it == 31) cshift = 0.45f * (cshift + exp2f(log2f(n2) * (1.0f/32.0f)));
      if (tid < 64){
        float inv = rsqrtf(n2);
        *(float4*)&xv[padf_(tid)] = make_float4(xx.x*inv, xx.y*inv, xx.z*inv, xx.w*inv);
      }
      __syncthreads();
    }
  }
  // final: sigma = ||K x||  (x normalized at it=127 renorm; fp32 rowk)
  {
    float py[4] = {0.f,0.f,0.f,0.f};
    #pragma unroll
    for (int j4=0;j4<16;j4++){
      float4 x4 = *(const float4*)&xv[padf_(cg*16 + j4)];
      #pragma unroll
      for (int i=0;i<4;i++){
        py[i] = fmaf(rowk[i][4*j4+0], x4.x, py[i]);
        py[i] = fmaf(rowk[i][4*j4+1], x4.y, py[i]);
        py[i] = fmaf(rowk[i][4*j4+2], x4.z, py[i]);
        py[i] = fmaf(rowk[i][4*j4+3], x4.w, py[i]);
      }
    }
    #pragma unroll
    for (int i=0;i<4;i++) py[i] = dpp_red4(py[i]);
    if (cg == 0)
      *(float4*)&yv[padf_(rg)] = make_float4(py[0],py[1],py[2],py[3]);
    __syncthreads();
    if (tid < 64){
      float4 yy = *(const float4*)&yv[padf_(tid)];
      float n2 = yy.x*yy.x + yy.y*yy.y + yy.z*yy.z + yy.w*yy.w;
      #pragma unroll
      for (int off=32; off>=1; off>>=1) n2 += __shfl_xor(n2, off);
      if (tid == 0) sig_out[m] = sqrtf(n2);
    }
  }
}

// ---------------------------------------------------------------------------
// GEMM: out[32768x128] = A[32768xKTOT] * Wpack^T, A built on the fly:
//   kk < 1024 : A[bt,kk] = pi[bt, kk>>7] * u[bt, kk&127]
//   kk >= 1024: A[bt,kk] = pi[bt,(kk-1024)>>7] * z[bt,(kk-1024)&127]
// epilogue scales by 1/scale.  128x128 tile, 4 waves, mfma 16x16x32 bf16.
// ---------------------------------------------------------------------------
template<int KTOT, bool SECOND>
__global__ __launch_bounds__(256) void gemm_kernel(
    const float* __restrict__ u, const float* __restrict__ zsrc,
    const float* __restrict__ pi, const unsigned short* __restrict__ wpack,
    float* __restrict__ out, const float* __restrict__ sig8)
{
  float inv_s = 1.0f / scale_from(sig8);
  __shared__ unsigned short a_lds[128*64];
  __shared__ unsigned short b_lds[128*64];
  const int tid  = threadIdx.x;
  const int lane = tid & 63;
  const int wid  = tid >> 6;
  const int wr   = wid >> 1, wc = wid & 1;
  const int bt0  = blockIdx.x * 128;
  f32x4 acc[4][4];
  #pragma unroll
  for (int a=0;a<4;a++){
    #pragma unroll
    for (int b=0;b<4;b++) acc[a][b] = (f32x4){0.f,0.f,0.f,0.f};
  }
  const int r = tid >> 1, half = tid & 1;
  for (int kk0 = 0; kk0 < KTOT; kk0 += 64){
    { // A-stage (reg-staged: fp32 load, *pi, ->bf16)
      const float* src; int mm, j0;
      if (!SECOND || kk0 < 1024){ mm = kk0 >> 7; j0 = (kk0 & 127) + half*32; src = u + (bt0+r)*D_ + j0; }
      else { int k2 = kk0 - 1024; mm = k2 >> 7; j0 = (k2 & 127) + half*32; src = zsrc + (bt0+r)*D_ + j0; }
      float pv = pi[(bt0+r)*M_ + mm];
      unsigned short* dst = &a_lds[r*64 + half*32];
      #pragma unroll
      for (int i=0;i<8;i++){
        float4 v = *(const float4*)(src + i*4);
        ushort4 w;
        w.x=f2bf(v.x*pv); w.y=f2bf(v.y*pv); w.z=f2bf(v.z*pv); w.w=f2bf(v.w*pv);
        *(ushort4*)(dst + i*4) = w;
      }
      // B-stage (bf16 pack, N x K row-major = B^T layout)
      const unsigned short* srcb = wpack + r*KTOT + kk0 + half*32;
      uint4* dstb = (uint4*)&b_lds[r*64 + half*32];
      #pragma unroll
      for (int i=0;i<4;i++) dstb[i] = *(const uint4*)(srcb + i*8);
    }
    __syncthreads();
    #pragma unroll
    for (int ks=0; ks<2; ks++){
      short8 af[4], bfr[4];
      #pragma unroll
      for (int f=0; f<4; f++){
        int ar_ = wr*64 + f*16 + (lane&15);
        af[f]  = *(const short8*)&a_lds[ar_*64 + ks*32 + (lane>>4)*8];
        int bn  = wc*64 + f*16 + (lane&15);
        bfr[f] = *(const short8*)&b_lds[bn*64 + ks*32 + (lane>>4)*8];
      }
      #pragma unroll
      for (int fr=0; fr<4; fr++){
        #pragma unroll
        for (int fc=0; fc<4; fc++)
          acc[fr][fc] = __builtin_amdgcn_mfma_f32_16x16x32_bf16(af[fr], bfr[fc], acc[fr][fc], 0,0,0);
      }
    }
    __syncthreads();
  }
  #pragma unroll
  for (int fr=0; fr<4; fr++){
    #pragma unroll
    for (int fc=0; fc<4; fc++){
      #pragma unroll
      for (int rr=0; rr<4; rr++){
        int row = bt0 + wr*64 + fr*16 + (lane>>4)*4 + rr;
        int col = wc*64 + fc*16 + (lane&15);
        out[row*D_ + col] = acc[fr][fc][rr]*inv_s;
      }
    }
  }
}

// ---------------------------------------------------------------------------
// Scan: 256 independent complex recurrences (block-diag 2x2 rotations).
// 3-phase exact chunked scan, NC_=256 chunks of 32.  v is in the y-region of
// d_out (already /scale).  Reference emits carry BEFORE consuming v[t].
// ---------------------------------------------------------------------------
__global__ void scan_a(const float* __restrict__ v, const float* __restrict__ rho_raw,
                       const float* __restrict__ theta, const float* __restrict__ sig8,
                       float* __restrict__ Ssum)
{
  int b = blockIdx.x >> 8, c = blockIdx.x & 255;
  int p = threadIdx.x;
  float sc  = scale_from(sig8);
  float rho = sigmoidf_(rho_raw[p]) * 0.999f / sc;
  float th  = theta[p];
  float ar = rho*cosf(th), ai = rho*sinf(th);
  const float2* vp = (const float2*)v + (b*T_ + c*LCH_)*64 + p;
  float zx=0.f, zy=0.f;
  #pragma unroll 8
  for (int t=0; t<LCH_; ++t){
    float2 vt = vp[t*64];
    float nx = fmaf(ar, zx, fmaf(-ai, zy, vt.x));
    float ny = fmaf(ai, zx, fmaf( ar, zy, vt.y));
    zx = nx; zy = ny;
  }
  ((float2*)Ssum)[(b*NC_ + c)*64 + p] = make_float2(zx, zy);
}

__global__ void scan_b(const float* __restrict__ Ssum, float* __restrict__ Zst,
                       const float* __restrict__ rho_raw, const float* __restrict__ theta,
                       const float* __restrict__ sig8)
{
  int tid = threadIdx.x;          // 256 = B_*64
  int b = tid >> 6, p = tid & 63;
  float sc  = scale_from(sig8);
  float rho = sigmoidf_(rho_raw[p]) * 0.999f / sc;
  float th  = theta[p];
  float qr = rho*cosf(th), qi = rho*sinf(th);
  #pragma unroll
  for (int s=0;s<5;s++){ float nr = qr*qr - qi*qi; float ni = 2.f*qr*qi; qr=nr; qi=ni; } // a^32
  float Zx=0.f, Zy=0.f;
  const float2* S = (const float2*)Ssum;
  float2* Z = (float2*)Zst;
  #pragma unroll 4
  for (int c=0;c<NC_;c++){
    Z[(b*NC_+c)*64 + p] = make_float2(Zx, Zy);
    float2 s = S[(b*NC_+c)*64 + p];
    float nx = qr*Zx - qi*Zy + s.x;
    float ny = qi*Zx + qr*Zy + s.y;
    Zx = nx; Zy = ny;
  }
}

__global__ void scan_c(const float* __restrict__ v, const float* __restrict__ Zst,
                       const float* __restrict__ rho_raw, const float* __restrict__ theta,
                       const float* __restrict__ sig8, float* __restrict__ zout)
{
  int b = blockIdx.x >> 8, c = blockIdx.x & 255;
  int p = threadIdx.x;
  float sc  = scale_from(sig8);
  float rho = sigmoidf_(rho_raw[p]) * 0.999f / sc;
  float th  = theta[p];
  float ar = rho*cosf(th), ai = rho*sinf(th);
  const float2* vp = (const float2*)v + (b*T_ + c*LCH_)*64 + p;
  float2*       zp = (float2*)zout    + (b*T_ + c*LCH_)*64 + p;
  float2 z0 = ((const float2*)Zst)[(b*NC_+c)*64 + p];
  float zx = z0.x, zy = z0.y;
  #pragma unroll 8
  for (int t=0; t<LCH_; ++t){
    zp[t*64] = make_float2(zx, zy);      // emit BEFORE consuming v[t]
    float2 vt = vp[t*64];
    float nx = fmaf(ar, zx, fmaf(-ai, zy, vt.x));
    float ny = fmaf(ai, zx, fmaf( ar, zy, vt.y));
    zx = nx; zy = ny;
  }
}

// ---------------------------------------------------------------------------
extern "C" void kernel_launch(void* const* d_in, const int* in_sizes, int n_in,
                              void* d_out, int out_size, void* d_ws, size_t ws_size,
                              hipStream_t stream)
{
  const float* u       = (const float*)d_in[0];
  const float* rho_raw = (const float*)d_in[1];
  const float* theta   = (const float*)d_in[2];
  const float* K12     = (const float*)d_in[3];
  const float* K21     = (const float*)d_in[4];
  const float* K22     = (const float*)d_in[5];
  const float* gate_w  = (const float*)d_in[6];
  const float* gate_b  = (const float*)d_in[7];
  float* out = (float*)d_out;
  char*  ws  = (char*)d_ws;
  float* sig8 = (float*)ws;
  float* pi   = (float*)(ws + WS_PI);
  unsigned short* w12 = (unsigned short*)(ws + WS_W12);
  unsigned short* w2  = (unsigned short*)(ws + WS_W2);
  float* Ssum = (float*)(ws + WS_S);
  float* Zst  = (float*)(ws + WS_ZST);
  float* v    = out;            // y-region doubles as v scratch until GEMM2
  float* zout = out + Z_OFF;

  hipLaunchKernelGGL(prep_kernel, dim3(BT_/4 + 384), dim3(256), 0, stream,
                     u, gate_w, gate_b, K12, K21, K22, pi, w12, w2);
  hipLaunchKernelGGL(sigma_kernel, dim3(8), dim3(256), 0, stream,
                     rho_raw, theta, K12, K21, K22, sig8);
  hipLaunchKernelGGL((gemm_kernel<1024,false>), dim3(256), dim3(256), 0, stream,
                     u, u, pi, w12, v, sig8);
  hipLaunchKernelGGL(scan_a, dim3(B_*NC_), dim3(64), 0, stream, v, rho_raw, theta, sig8, Ssum);
  hipLaunchKernelGGL(scan_b, dim3(1), dim3(256), 0, stream, Ssum, Zst, rho_raw, theta, sig8);
  hipLaunchKernelGGL(scan_c, dim3(B_*NC_), dim3(64), 0, stream, v, Zst, rho_raw, theta, sig8, zout);
  hipLaunchKernelGGL((gemm_kernel<2048,true>), dim3(256), dim3(256), 0, stream,
                     u, zout, pi, w2, out, sig8);
}

// Round 3
// 807.588 us; speedup vs baseline: 2.0497x; 1.0537x over previous
//
#include <hip/hip_runtime.h>
#include <hip/hip_bf16.h>
#include <cstdint>

// ---------------------------------------------------------------------------
// Problem constants
// ---------------------------------------------------------------------------
#define B_   4
#define T_   8192
#define D_   128
#define M_   8
#define BT_  (B_*T_)          // 32768 tokens
#define NC_  256              // scan chunks (32 steps each)
#define LCH_ (T_/NC_)         // 32 steps/chunk
#define Z_OFF (BT_*D_)        // d_out: [y (BT*D)] [z (BT*D)]

// workspace layout (bytes)
#define WS_PI    256
#define WS_W12   (WS_PI  + BT_*M_*4)        // 128x1024 bf16
#define WS_W2    (WS_W12 + 128*1024*2)      // 128x2048 bf16
#define WS_S     (WS_W2  + 128*2048*2)      // chunk end-states
#define WS_ZST   (WS_S   + NC_*B_*64*2*4)   // chunk start-states
// total ~2.8 MB

typedef float f32x4 __attribute__((ext_vector_type(4)));
typedef short short8 __attribute__((ext_vector_type(8)));

__device__ __forceinline__ unsigned short f2bf(float f){
  union { float f; uint32_t u; } v; v.f = f;
  return (unsigned short)((v.u + 0x7FFFu + ((v.u >> 16) & 1u)) >> 16);
}
__device__ __forceinline__ float sigmoidf_(float x){ return 1.0f/(1.0f + __expf(-x)); }
__device__ __forceinline__ float scale_from(const float* s8){
  float s = 1.0f;
  #pragma unroll
  for (int m=0;m<M_;m++) s = fmaxf(s, s8[m]);
  return s;
}
// butterfly add over lane bits 0,1 via DPP quad_perm (VALU-only, no DS)
__device__ __forceinline__ float dpp_red4(float x){
  x += __int_as_float(__builtin_amdgcn_mov_dpp(__float_as_int(x), 0xB1, 0xF, 0xF, 1)); // xor 1
  x += __int_as_float(__builtin_amdgcn_mov_dpp(__float_as_int(x), 0x4E, 0xF, 0xF, 1)); // xor 2
  return x;
}

// ---------------------------------------------------------------------------
// K1: gate softmax pi + weight packing (bf16)
// ---------------------------------------------------------------------------
__global__ void prep_kernel(const float* __restrict__ u,
                            const float* __restrict__ gate_w,
                            const float* __restrict__ gate_b,
                            const float* __restrict__ K12,
                            const float* __restrict__ K21,
                            const float* __restrict__ K22,
                            float* __restrict__ pi_out,
                            unsigned short* __restrict__ w12,
                            unsigned short* __restrict__ w2)
{
  int bid = blockIdx.x;
  if (bid < BT_/4) {
    int wid = threadIdx.x >> 6, lane = threadIdx.x & 63;
    int bt = bid*4 + wid;
    float2 u2 = *(const float2*)(u + bt*D_ + lane*2);
    float lg[M_];
    #pragma unroll
    for (int m=0;m<M_;m++){
      float2 g2 = *(const float2*)(gate_w + m*D_ + lane*2);
      lg[m] = u2.x*g2.x + u2.y*g2.y;
    }
    #pragma unroll
    for (int off=32; off>=1; off>>=1){
      #pragma unroll
      for (int m=0;m<M_;m++) lg[m] += __shfl_xor(lg[m], off);
    }
    #pragma unroll
    for (int m=0;m<M_;m++) lg[m] += gate_b[m];
    float mx = lg[0];
    #pragma unroll
    for (int m=1;m<M_;m++) mx = fmaxf(mx, lg[m]);
    float e[M_]; float s = 0.f;
    #pragma unroll
    for (int m=0;m<M_;m++){ e[m] = __expf(lg[m]-mx); s += e[m]; }
    float inv = 1.0f/s;
    if (lane == 0){
      float* po = pi_out + bt*M_;
      *(float4*)(po)   = make_float4(e[0]*inv,e[1]*inv,e[2]*inv,e[3]*inv);
      *(float4*)(po+4) = make_float4(e[4]*inv,e[5]*inv,e[6]*inv,e[7]*inv);
    }
  } else {
    int idx = (bid - BT_/4)*1024 + threadIdx.x*4;
    #pragma unroll
    for (int t=0;t<4;t++){
      int i = idx + t;
      if (i < 128*1024){                   // W12[s, m*128+u] = K12[m,s,u]
        int s_ = i >> 10, kk = i & 1023;
        int mm = kk >> 7, uu = kk & 127;
        w12[i] = f2bf(K12[(mm*D_ + s_)*D_ + uu]);
      } else {                             // W2[y, kk]: kk<1024 -> K22, else K21
        int j = i - 128*1024;
        int y_ = j >> 11, kk = j & 2047;
        float val;
        if (kk < 1024){ int mm = kk>>7, uu = kk&127; val = K22[(mm*D_ + y_)*D_ + uu]; }
        else { int kk2 = kk-1024; int mm = kk2>>7, ss = kk2&127; val = K21[(mm*D_ + y_)*D_ + ss]; }
        w2[j] = f2bf(val);
      }
    }
  }
}

// ---------------------------------------------------------------------------
// K2: sigma_max per expert via shifted power iteration on B = K^T K.
// 512 threads (8 waves = 2/SIMD -> 256 arch-VGPR cap, fits WITHOUT spill).
// Thread (rg=tid>>2, cg=tid&3) owns rows r0=2*rg..+1 x cols c0=64*cg..+63:
// rowk fp32 [2][64] (128 regs), colk = K^T tile bf16-packed [2][32] (64 regs).
// Deferred normalization (every 16 iters), 2 barriers/iter, DPP reduce over
// the 2 cg lane-bits.  Final sigma = ||K x||.
// ---------------------------------------------------------------------------
#define SIG_IT 128
// x/y vectors: 64 float4 units, padded 16B every 8 units -> conflict-free b128
__device__ __forceinline__ int padf_(int unit){ return unit*4 + (unit>>3)*4; }

__global__ __launch_bounds__(512, 1) void sigma_kernel(
    const float* __restrict__ rho_raw, const float* __restrict__ theta,
    const float* __restrict__ K12, const float* __restrict__ K21,
    const float* __restrict__ K22, float* __restrict__ sig_out)
{
  __shared__ float xv[304], yv[304];
  __shared__ float red[1];
  const int m   = blockIdx.x;
  const int tid = threadIdx.x;
  const int rg  = tid >> 2;      // 0..127 : 2 rows each
  const int cg  = tid & 3;       // 0..3   : 64 cols each
  const int r0  = rg*2;
  const int c0  = cg*64;
  const bool rlow = (r0 < 128), clow = (c0 < 128);

  // rotation-pair params for this thread's row pair (pair index = rg when rlow)
  float rc=0.f, rs=0.f;
  if (rlow){
    float rho = sigmoidf_(rho_raw[rg]) * 0.999f;
    rc = rho*cosf(theta[rg]);  rs = rho*sinf(theta[rg]);
  }

  // ---- rowk[i][j] = K[r0+i][c0+j]  (fp32, 128 VGPRs)
  float rowk[2][64];
  if (rlow && clow) {
    #pragma unroll
    for (int i=0;i<2;i++){
      float v0 = i ? rs : rc;        // col 2*rg
      float v1 = i ? rc : -rs;       // col 2*rg+1
      #pragma unroll
      for (int j=0;j<64;j++){
        int c = c0 + j;
        rowk[i][j] = (c == 2*rg) ? v0 : ((c == 2*rg+1) ? v1 : 0.0f);
      }
    }
  } else {
    const float* base;
    if (rlow)      base = K12 + (m*128 + r0)*128       + (c0 - 128);
    else if (clow) base = K21 + (m*128 + (r0-128))*128 + c0;
    else           base = K22 + (m*128 + (r0-128))*128 + (c0 - 128);
    #pragma unroll
    for (int i=0;i<2;i++){
      #pragma unroll
      for (int j4=0;j4<16;j4++){
        float4 v = *(const float4*)(base + i*128 + j4*4);
        rowk[i][4*j4+0]=v.x; rowk[i][4*j4+1]=v.y; rowk[i][4*j4+2]=v.z; rowk[i][4*j4+3]=v.w;
      }
    }
  }

  // ---- colk[i][kk] = pack_bf16( K[c0+2kk][r0+i], K[c0+2kk+1][r0+i] )
  uint32_t colk[2][32];
  {
    const float* base2 = nullptr; int roff = 0;
    if (clow && !rlow)      { base2 = K12 + m*128*128; roff = r0 - 128; } // a<128, b right half
    else if (!clow && rlow) { base2 = K21 + m*128*128; roff = r0;       } // a>=128, b left half
    else if (!clow && !rlow){ base2 = K22 + m*128*128; roff = r0 - 128; }
    #pragma unroll
    for (int kk=0; kk<32; ++kk){
      int a0 = c0 + 2*kk, a1 = a0 + 1;
      float va[2], vb[2];
      if (rlow && clow){                    // K11[a][b], b = r0+i (pair rg)
        #pragma unroll
        for (int i=0;i<2;i++){
          int b = r0 + i;
          va[i] = ((a0>>1)==rg) ? ( (((a0^b)&1)==0) ? rc : ((a0&1)? rs : -rs) ) : 0.f;
          vb[i] = ((a1>>1)==rg) ? ( (((a1^b)&1)==0) ? rc : ((a1&1)? rs : -rs) ) : 0.f;
        }
      } else {
        int aa0 = clow ? a0 : a0-128, aa1 = clow ? a1 : a1-128;
        float2 f0 = *(const float2*)(base2 + aa0*128 + roff);
        float2 f1 = *(const float2*)(base2 + aa1*128 + roff);
        va[0]=f0.x; va[1]=f0.y;
        vb[0]=f1.x; vb[1]=f1.y;
      }
      #pragma unroll
      for (int i=0;i<2;i++)
        colk[i][kk] = (uint32_t)f2bf(va[i]) | ((uint32_t)f2bf(vb[i]) << 16);
    }
  }

  // ---- init x (unnormalized)
  if (tid < 256)
    xv[padf_(tid>>2) + (tid&3)] = 1.0f + 0.25f*__sinf(0.731f*(float)tid);
  __syncthreads();

  const int u_  = rg >> 1;           // float4 unit holding this thread's 2 rows
  const int o_  = (rg & 1) * 2;      // offset within unit
  float cshift = 0.0f;
  for (int it=0; it<SIG_IT; ++it){
    // phase 1: y = K x
    float py0=0.f, py1=0.f;
    #pragma unroll
    for (int j4=0;j4<16;j4++){
      float4 x4 = *(const float4*)&xv[padf_(cg*16 + j4)];
      py0 = fmaf(rowk[0][4*j4+0], x4.x, py0);
      py0 = fmaf(rowk[0][4*j4+1], x4.y, py0);
      py0 = fmaf(rowk[0][4*j4+2], x4.z, py0);
      py0 = fmaf(rowk[0][4*j4+3], x4.w, py0);
      py1 = fmaf(rowk[1][4*j4+0], x4.x, py1);
      py1 = fmaf(rowk[1][4*j4+1], x4.y, py1);
      py1 = fmaf(rowk[1][4*j4+2], x4.z, py1);
      py1 = fmaf(rowk[1][4*j4+3], x4.w, py1);
    }
    py0 = dpp_red4(py0); py1 = dpp_red4(py1);
    if (cg == 0)
      *(float2*)&yv[padf_(u_) + o_] = make_float2(py0, py1);
    __syncthreads();
    // phase 2: x' = K^T y - cshift*x   (colk bf16)
    float px0=0.f, px1=0.f;
    #pragma unroll
    for (int kk=0;kk<16;kk++){
      float4 y4 = *(const float4*)&yv[padf_(cg*16 + kk)];
      #pragma unroll
      for (int i=0;i<2;i++){
        uint32_t p0 = colk[i][2*kk], p1 = colk[i][2*kk+1];
        float t = (i==0)? 0.f : 0.f; (void)t;
        float acc = (i==0)? px0 : px1;
        acc = fmaf(__int_as_float((int)(p0 << 16)),         y4.x, acc);
        acc = fmaf(__int_as_float((int)(p0 & 0xffff0000u)), y4.y, acc);
        acc = fmaf(__int_as_float((int)(p1 << 16)),         y4.z, acc);
        acc = fmaf(__int_as_float((int)(p1 & 0xffff0000u)), y4.w, acc);
        if (i==0) px0 = acc; else px1 = acc;
      }
    }
    px0 = dpp_red4(px0); px1 = dpp_red4(px1);
    if (cg == 0){
      float2 xo = *(const float2*)&xv[padf_(u_) + o_];
      *(float2*)&xv[padf_(u_) + o_] = make_float2(px0 - cshift*xo.x, px1 - cshift*xo.y);
    }
    __syncthreads();
    // renormalize every 16 iters; set shift from norm growth at it==31
    if ((it & 15) == 15){
      float4 xx;
      if (tid < 64){
        xx = *(const float4*)&xv[padf_(tid)];
        float n2 = xx.x*xx.x + xx.y*xx.y + xx.z*xx.z + xx.w*xx.w;
        #pragma unroll
        for (int off=32; off>=1; off>>=1) n2 += __shfl_xor(n2, off);
        if (tid == 0) red[0] = n2;
      }
      __syncthreads();
      float n2 = red[0];
      if (it == 31) cshift = 0.45f * (cshift + exp2f(log2f(n2) * (1.0f/32.0f)));
      if (tid < 64){
        float inv = rsqrtf(n2);
        *(float4*)&xv[padf_(tid)] = make_float4(xx.x*inv, xx.y*inv, xx.z*inv, xx.w*inv);
      }
      __syncthreads();
    }
  }
  // final: sigma = ||K x||  (x normalized at it=127 renorm; fp32 rowk)
  {
    float py0=0.f, py1=0.f;
    #pragma unroll
    for (int j4=0;j4<16;j4++){
      float4 x4 = *(const float4*)&xv[padf_(cg*16 + j4)];
      py0 = fmaf(rowk[0][4*j4+0], x4.x, py0);
      py0 = fmaf(rowk[0][4*j4+1], x4.y, py0);
      py0 = fmaf(rowk[0][4*j4+2], x4.z, py0);
      py0 = fmaf(rowk[0][4*j4+3], x4.w, py0);
      py1 = fmaf(rowk[1][4*j4+0], x4.x, py1);
      py1 = fmaf(rowk[1][4*j4+1], x4.y, py1);
      py1 = fmaf(rowk[1][4*j4+2], x4.z, py1);
      py1 = fmaf(rowk[1][4*j4+3], x4.w, py1);
    }
    py0 = dpp_red4(py0); py1 = dpp_red4(py1);
    if (cg == 0)
      *(float2*)&yv[padf_(u_) + o_] = make_float2(py0, py1);
    __syncthreads();
    if (tid < 64){
      float4 yy = *(const float4*)&yv[padf_(tid)];
      float n2 = yy.x*yy.x + yy.y*yy.y + yy.z*yy.z + yy.w*yy.w;
      #pragma unroll
      for (int off=32; off>=1; off>>=1) n2 += __shfl_xor(n2, off);
      if (tid == 0) sig_out[m] = sqrtf(n2);
    }
  }
}

// ---------------------------------------------------------------------------
// GEMM: out[32768x128] = A[32768xKTOT] * Wpack^T, A built on the fly:
//   kk < 1024 : A[bt,kk] = pi[bt, kk>>7] * u[bt, kk&127]
//   kk >= 1024: A[bt,kk] = pi[bt,(kk-1024)>>7] * z[bt,(kk-1024)&127]
// epilogue scales by 1/scale.  128x128 tile, 4 waves, mfma 16x16x32 bf16.
// ---------------------------------------------------------------------------
template<int KTOT, bool SECOND>
__global__ __launch_bounds__(256) void gemm_kernel(
    const float* __restrict__ u, const float* __restrict__ zsrc,
    const float* __restrict__ pi, const unsigned short* __restrict__ wpack,
    float* __restrict__ out, const float* __restrict__ sig8)
{
  float inv_s = 1.0f / scale_from(sig8);
  __shared__ unsigned short a_lds[128*64];
  __shared__ unsigned short b_lds[128*64];
  const int tid  = threadIdx.x;
  const int lane = tid & 63;
  const int wid  = tid >> 6;
  const int wr   = wid >> 1, wc = wid & 1;
  const int bt0  = blockIdx.x * 128;
  f32x4 acc[4][4];
  #pragma unroll
  for (int a=0;a<4;a++){
    #pragma unroll
    for (int b=0;b<4;b++) acc[a][b] = (f32x4){0.f,0.f,0.f,0.f};
  }
  const int r = tid >> 1, half = tid & 1;
  for (int kk0 = 0; kk0 < KTOT; kk0 += 64){
    { // A-stage (reg-staged: fp32 load, *pi, ->bf16)
      const float* src; int mm, j0;
      if (!SECOND || kk0 < 1024){ mm = kk0 >> 7; j0 = (kk0 & 127) + half*32; src = u + (bt0+r)*D_ + j0; }
      else { int k2 = kk0 - 1024; mm = k2 >> 7; j0 = (k2 & 127) + half*32; src = zsrc + (bt0+r)*D_ + j0; }
      float pv = pi[(bt0+r)*M_ + mm];
      unsigned short* dst = &a_lds[r*64 + half*32];
      #pragma unroll
      for (int i=0;i<8;i++){
        float4 v = *(const float4*)(src + i*4);
        ushort4 w;
        w.x=f2bf(v.x*pv); w.y=f2bf(v.y*pv); w.z=f2bf(v.z*pv); w.w=f2bf(v.w*pv);
        *(ushort4*)(dst + i*4) = w;
      }
      // B-stage (bf16 pack, N x K row-major = B^T layout)
      const unsigned short* srcb = wpack + r*KTOT + kk0 + half*32;
      uint4* dstb = (uint4*)&b_lds[r*64 + half*32];
      #pragma unroll
      for (int i=0;i<4;i++) dstb[i] = *(const uint4*)(srcb + i*8);
    }
    __syncthreads();
    #pragma unroll
    for (int ks=0; ks<2; ks++){
      short8 af[4], bfr[4];
      #pragma unroll
      for (int f=0; f<4; f++){
        int ar_ = wr*64 + f*16 + (lane&15);
        af[f]  = *(const short8*)&a_lds[ar_*64 + ks*32 + (lane>>4)*8];
        int bn  = wc*64 + f*16 + (lane&15);
        bfr[f] = *(const short8*)&b_lds[bn*64 + ks*32 + (lane>>4)*8];
      }
      #pragma unroll
      for (int fr=0; fr<4; fr++){
        #pragma unroll
        for (int fc=0; fc<4; fc++)
          acc[fr][fc] = __builtin_amdgcn_mfma_f32_16x16x32_bf16(af[fr], bfr[fc], acc[fr][fc], 0,0,0);
      }
    }
    __syncthreads();
  }
  #pragma unroll
  for (int fr=0; fr<4; fr++){
    #pragma unroll
    for (int fc=0; fc<4; fc++){
      #pragma unroll
      for (int rr=0; rr<4; rr++){
        int row = bt0 + wr*64 + fr*16 + (lane>>4)*4 + rr;
        int col = wc*64 + fc*16 + (lane&15);
        out[row*D_ + col] = acc[fr][fc][rr]*inv_s;
      }
    }
  }
}

// ---------------------------------------------------------------------------
// Scan: 256 independent complex recurrences (block-diag 2x2 rotations).
// 3-phase exact chunked scan, NC_=256 chunks of 32.  v is in the y-region of
// d_out (already /scale).  Reference emits carry BEFORE consuming v[t].
// ---------------------------------------------------------------------------
__global__ void scan_a(const float* __restrict__ v, const float* __restrict__ rho_raw,
                       const float* __restrict__ theta, const float* __restrict__ sig8,
                       float* __restrict__ Ssum)
{
  int b = blockIdx.x >> 8, c = blockIdx.x & 255;
  int p = threadIdx.x;
  float sc  = scale_from(sig8);
  float rho = sigmoidf_(rho_raw[p]) * 0.999f / sc;
  float th  = theta[p];
  float ar = rho*cosf(th), ai = rho*sinf(th);
  const float2* vp = (const float2*)v + (b*T_ + c*LCH_)*64 + p;
  float zx=0.f, zy=0.f;
  #pragma unroll 8
  for (int t=0; t<LCH_; ++t){
    float2 vt = vp[t*64];
    float nx = fmaf(ar, zx, fmaf(-ai, zy, vt.x));
    float ny = fmaf(ai, zx, fmaf( ar, zy, vt.y));
    zx = nx; zy = ny;
  }
  ((float2*)Ssum)[(b*NC_ + c)*64 + p] = make_float2(zx, zy);
}

__global__ void scan_b(const float* __restrict__ Ssum, float* __restrict__ Zst,
                       const float* __restrict__ rho_raw, const float* __restrict__ theta,
                       const float* __restrict__ sig8)
{
  int tid = threadIdx.x;          // 256 = B_*64
  int b = tid >> 6, p = tid & 63;
  float sc  = scale_from(sig8);
  float rho = sigmoidf_(rho_raw[p]) * 0.999f / sc;
  float th  = theta[p];
  float qr = rho*cosf(th), qi = rho*sinf(th);
  #pragma unroll
  for (int s=0;s<5;s++){ float nr = qr*qr - qi*qi; float ni = 2.f*qr*qi; qr=nr; qi=ni; } // a^32
  float Zx=0.f, Zy=0.f;
  const float2* S = (const float2*)Ssum;
  float2* Z = (float2*)Zst;
  #pragma unroll 4
  for (int c=0;c<NC_;c++){
    Z[(b*NC_+c)*64 + p] = make_float2(Zx, Zy);
    float2 s = S[(b*NC_+c)*64 + p];
    float nx = qr*Zx - qi*Zy + s.x;
    float ny = qi*Zx + qr*Zy + s.y;
    Zx = nx; Zy = ny;
  }
}

__global__ void scan_c(const float* __restrict__ v, const float* __restrict__ Zst,
                       const float* __restrict__ rho_raw, const float* __restrict__ theta,
                       const float* __restrict__ sig8, float* __restrict__ zout)
{
  int b = blockIdx.x >> 8, c = blockIdx.x & 255;
  int p = threadIdx.x;
  float sc  = scale_from(sig8);
  float rho = sigmoidf_(rho_raw[p]) * 0.999f / sc;
  float th  = theta[p];
  float ar = rho*cosf(th), ai = rho*sinf(th);
  const float2* vp = (const float2*)v + (b*T_ + c*LCH_)*64 + p;
  float2*       zp = (float2*)zout    + (b*T_ + c*LCH_)*64 + p;
  float2 z0 = ((const float2*)Zst)[(b*NC_+c)*64 + p];
  float zx = z0.x, zy = z0.y;
  #pragma unroll 8
  for (int t=0; t<LCH_; ++t){
    zp[t*64] = make_float2(zx, zy);      // emit BEFORE consuming v[t]
    float2 vt = vp[t*64];
    float nx = fmaf(ar, zx, fmaf(-ai, zy, vt.x));
    float ny = fmaf(ai, zx, fmaf( ar, zy, vt.y));
    zx = nx; zy = ny;
  }
}

// ---------------------------------------------------------------------------
extern "C" void kernel_launch(void* const* d_in, const int* in_sizes, int n_in,
                              void* d_out, int out_size, void* d_ws, size_t ws_size,
                              hipStream_t stream)
{
  const float* u       = (const float*)d_in[0];
  const float* rho_raw = (const float*)d_in[1];
  const float* theta   = (const float*)d_in[2];
  const float* K12     = (const float*)d_in[3];
  const float* K21     = (const float*)d_in[4];
  const float* K22     = (const float*)d_in[5];
  const float* gate_w  = (const float*)d_in[6];
  const float* gate_b  = (const float*)d_in[7];
  float* out = (float*)d_out;
  char*  ws  = (char*)d_ws;
  float* sig8 = (float*)ws;
  float* pi   = (float*)(ws + WS_PI);
  unsigned short* w12 = (unsigned short*)(ws + WS_W12);
  unsigned short* w2  = (unsigned short*)(ws + WS_W2);
  float* Ssum = (float*)(ws + WS_S);
  float* Zst  = (float*)(ws + WS_ZST);
  float* v    = out;            // y-region doubles as v scratch until GEMM2
  float* zout = out + Z_OFF;

  hipLaunchKernelGGL(prep_kernel, dim3(BT_/4 + 384), dim3(256), 0, stream,
                     u, gate_w, gate_b, K12, K21, K22, pi, w12, w2);
  hipLaunchKernelGGL(sigma_kernel, dim3(8), dim3(512), 0, stream,
                     rho_raw, theta, K12, K21, K22, sig8);
  hipLaunchKernelGGL((gemm_kernel<1024,false>), dim3(256), dim3(256), 0, stream,
                     u, u, pi, w12, v, sig8);
  hipLaunchKernelGGL(scan_a, dim3(B_*NC_), dim3(64), 0, stream, v, rho_raw, theta, sig8, Ssum);
  hipLaunchKernelGGL(scan_b, dim3(1), dim3(256), 0, stream, Ssum, Zst, rho_raw, theta, sig8);
  hipLaunchKernelGGL(scan_c, dim3(B_*NC_), dim3(64), 0, stream, v, Zst, rho_raw, theta, sig8, zout);
  hipLaunchKernelGGL((gemm_kernel<2048,true>), dim3(256), dim3(256), 0, stream,
                     u, zout, pi, w2, out, sig8);
}